// Round 5
// baseline (591.342 us; speedup 1.0000x reference)
//
#include <hip/hip_runtime.h>
#include <hip/hip_bf16.h>
#include <cstdint>
#include <cstddef>

typedef unsigned short u16;
typedef __attribute__((ext_vector_type(8))) __bf16 bf16x8;
typedef __attribute__((ext_vector_type(4))) float f32x4;

#define EPS_BN 1e-5f

__device__ __forceinline__ u16 f2bf(float f) {
    union { float f; uint32_t u; } v; v.f = f;
    uint32_t u = v.u;
    u += 0x7FFFu + ((u >> 16) & 1u);   // round-to-nearest-even
    return (u16)(u >> 16);
}
__device__ __forceinline__ float bf2f(u16 s) {
    union { uint32_t u; float f; } v; v.u = ((uint32_t)s) << 16;
    return v.f;
}

union Pack8 { u16 u[8]; uint4 v4; };
union Pack4 { u16 u[4]; uint2 v2; };

// async global -> LDS, 16B per lane; LDS dest = wave-uniform base + lane*16
typedef __attribute__((address_space(1))) const unsigned char as1c;
typedef __attribute__((address_space(3))) unsigned char as3;
__device__ __forceinline__ void gld_lds16(const void* g, void* l) {
    __builtin_amdgcn_global_load_lds((as1c*)g, (as3*)l, 16, 0, 0);
}

// ---------------------------------------------------------------------------
// Transpose NCHW fp32 -> NHWC bf16 via LDS tile.
// Block = 256 threads = 4 waves; tile = 64 pixels x 256 channels of batch b.
// Phase A (read): wave w = channels w*64..+63, lane = pixel -> 64 coalesced
//   256B reads per wave; convert to bf16; write 16B chunks to LDS with
//   chunk XOR (row&31) swizzle.
// Phase B (store): lane&31 = chunk, lane>>5 selects pixel -> each wave-store
//   is 1KB contiguous (2 pixels x 512B), full 64B lines, no amplification.
// ---------------------------------------------------------------------------
__device__ __forceinline__ void tr_tile(const float* __restrict__ in,
                                        u16* __restrict__ out,
                                        int P, int b, int p0)
{
    __shared__ u16 t_lds[64 * 256];        // 32 KB
    const int tid = threadIdx.x;
    const int w  = tid >> 6;               // wave: channel block w*64
    const int ln = tid & 63;               // lane: pixel p0+ln

    {
        const int p  = p0 + ln;
        const int pc = (p < P) ? p : (P - 1);   // clamp read, store guarded
        const float* ib = in + ((size_t)b * 256 + w * 64) * P + pc;
        #pragma unroll
        for (int k = 0; k < 8; k++) {
            Pack8 pk;
            #pragma unroll
            for (int i = 0; i < 8; i++)
                pk.u[i] = f2bf(ib[(size_t)(k * 8 + i) * P]);
            const int chunk = w * 8 + k;        // 16B chunk 0..31
            *(uint4*)&t_lds[ln * 256 + ((chunk ^ (ln & 31)) * 8)] = pk.v4;
        }
    }
    __syncthreads();
    {
        const int ch = tid & 31;               // chunk
        const int pg = tid >> 5;               // 0..7
        #pragma unroll
        for (int it = 0; it < 8; it++) {
            int px = it * 8 + pg;
            int p  = p0 + px;
            uint4 v = *(const uint4*)&t_lds[px * 256 + ((ch ^ (px & 31)) * 8)];
            if (p < P)
                *(uint4*)(out + ((size_t)(b * P + p)) * 256 + ch * 8) = v;
        }
    }
}

__global__ __launch_bounds__(256)
void tr_all(const float* __restrict__ s, const float* __restrict__ k,
            u16* __restrict__ so, u16* __restrict__ ko)
{
    int blk = blockIdx.x;
    if (blk < 2048) {
        tr_tile(s, so, 961, blk >> 4, (blk & 15) * 64);
    } else {
        tr_tile(k, ko, 49, blk - 2048, 0);
    }
}

// ---------------------------------------------------------------------------
// Implicit-im2col GEMM, NHWC bf16 input (old 128x128 / 4-wave structure).
// Kept for stages 1, 4, 5 (small-N or short-K launches).
// ---------------------------------------------------------------------------
template<int TAPS, bool NHWC_OUT, typename OutT, bool RELU>
__global__ __launch_bounds__(256)
void conv_gemm(const u16* __restrict__ in, const u16* __restrict__ W,
               const float* __restrict__ scale, const float* __restrict__ shift,
               OutT* __restrict__ out, int Hi, int Wi, int Ho, int Wo)
{
    constexpr int KT = TAPS * 256;
    constexpr int KB = KT / 64;
    const int HoWo = Ho * Wo;

    __shared__ u16 Alds[8192];
    __shared__ u16 Blds[8192];

    const int tid = threadIdx.x;
    const int it = blockIdx.x;
    const int jt = blockIdx.y;
    const int wv = tid >> 6;
    const int lane = tid & 63;

    const int c8 = tid & 7;
    const int t3 = tid >> 3;
    const int csw = c8 ^ (t3 & 7);

    const u16* gA[4];
    const u16* gB[4];
    #pragma unroll
    for (int q = 0; q < 4; q++) {
        int r = q * 32 + t3;
        gA[q] = W + (size_t)(it * 128 + r) * KT + csw * 8;
        int jg = jt * 128 + r;
        int bb = jg / HoWo;
        int msp = jg - bb * HoWo;
        int oyp = msp / Wo;
        int oxp = msp - oyp * Wo;
        gB[q] = in + ((size_t)(bb * Hi + oyp) * Wi + oxp) * 256 + csw * 8;
    }

    const int wi = (wv >> 1) * 64;
    const int wj = (wv & 1) * 64;
    const int lr = lane & 15;
    const int lq = lane >> 4;

    f32x4 acc[4][4];
    #pragma unroll
    for (int a = 0; a < 4; a++)
        #pragma unroll
        for (int b = 0; b < 4; b++)
            acc[a][b] = (f32x4){0.f, 0.f, 0.f, 0.f};

    for (int kb = 0; kb < KB; kb++) {
        const int tap = (TAPS == 1) ? 0 : (kb >> 2);
        const int c0  = (TAPS == 1) ? (kb * 64) : ((kb & 3) * 64);
        int ky = 0, kx = 0;
        if (TAPS == 9) { ky = tap / 3; kx = tap - ky * 3; }
        const int aoff = tap * 256 + c0;
        const int boff = (ky * Wi + kx) * 256 + c0;
        __syncthreads();
        #pragma unroll
        for (int q = 0; q < 4; q++)
            gld_lds16(gA[q] + aoff, Alds + q * 2048 + wv * 512);
        #pragma unroll
        for (int q = 0; q < 4; q++)
            gld_lds16(gB[q] + boff, Blds + q * 2048 + wv * 512);
        __syncthreads();
        #pragma unroll
        for (int ks = 0; ks < 2; ks++) {
            bf16x8 af[4], bfr[4];
            const int ck = ks * 4 + lq;
            #pragma unroll
            for (int f = 0; f < 4; f++) {
                int ra = wi + f * 16 + lr;
                af[f]  = *(const bf16x8*)&Alds[ra * 64 + ((ck ^ (ra & 7)) * 8)];
                int rb = wj + f * 16 + lr;
                bfr[f] = *(const bf16x8*)&Blds[rb * 64 + ((ck ^ (rb & 7)) * 8)];
            }
            #pragma unroll
            for (int fi = 0; fi < 4; fi++)
                #pragma unroll
                for (int fj = 0; fj < 4; fj++)
                    acc[fi][fj] = __builtin_amdgcn_mfma_f32_16x16x32_bf16(
                        af[fi], bfr[fj], acc[fi][fj], 0, 0, 0);
        }
    }

    if constexpr (NHWC_OUT) {
        int jc[4];
        #pragma unroll
        for (int fj = 0; fj < 4; fj++) jc[fj] = jt * 128 + wj + fj * 16 + lr;
        #pragma unroll
        for (int fi = 0; fi < 4; fi++) {
            int rb = it * 128 + wi + fi * 16 + lq * 4;
            f32x4 sc = *(const f32x4*)&scale[rb];
            f32x4 sh = *(const f32x4*)&shift[rb];
            #pragma unroll
            for (int fj = 0; fj < 4; fj++) {
                Pack4 pk;
                #pragma unroll
                for (int reg = 0; reg < 4; reg++) {
                    float v = acc[fi][fj][reg] * sc[reg] + sh[reg];
                    if (RELU) v = fmaxf(v, 0.f);
                    pk.u[reg] = f2bf(v);
                }
                *(uint2*)&((u16*)out)[(size_t)jc[fj] * 256 + rb] = pk.v2;
            }
        }
    } else {
        int jcb[4], jcm[4];
        #pragma unroll
        for (int fj = 0; fj < 4; fj++) {
            int jc = jt * 128 + wj + fj * 16 + lr;
            int b = jc / HoWo;
            jcb[fj] = b; jcm[fj] = jc - b * HoWo;
        }
        #pragma unroll
        for (int fi = 0; fi < 4; fi++) {
            int rb = it * 128 + wi + fi * 16 + lq * 4;
            f32x4 sc = *(const f32x4*)&scale[rb];
            f32x4 sh = *(const f32x4*)&shift[rb];
            #pragma unroll
            for (int reg = 0; reg < 4; reg++) {
                int r = rb + reg;
                #pragma unroll
                for (int fj = 0; fj < 4; fj++) {
                    float v = acc[fi][fj][reg] * sc[reg] + sh[reg];
                    if (RELU) v = fmaxf(v, 0.f);
                    size_t o = ((size_t)(jcb[fj] * 256 + r)) * HoWo + jcm[fj];
                    ((float*)out)[o] = v;
                }
            }
        }
    }
}

// ---------------------------------------------------------------------------
// 256x256-tile pipelined implicit-im2col GEMM, 4 waves x 128x128 output each.
// Rationale: the 8-wave version was LDS-read-BW-bound (192 KB frag reads per
// K-tile per CU ~= 1714 cyc vs 620 cyc MFMA -> 34% MfmaUtil cap, measured).
// 4 waves x 128x128 cuts frag traffic to 128 KB/K-tile (cap ~54%).
// Per K-tile: issue all 32 ds_reads (a0,b0,b1,a1) + stage j+1 h1; counted
// lgkm(15/8/0) lets later phases' reads fly under earlier MFMA (15 is the
// max encodable lgkmcnt on gfx9 -- waits for 17 of 32, needs first 16).
// 3 barriers: B2 (B-slot reads done -> STB j+2 h0 safe), B3 (A-slot reads
// done -> STA safe), B4 (vmcnt(8): j+1 fully staged before next ds_reads).
// Safety is data-dep based (each wave's frag reads complete before its own
// MFMA, which precedes its barrier arrival) -> independent of compiler
// scheduling of the loads.
// ---------------------------------------------------------------------------
template<int TAPS>
__global__ __launch_bounds__(256, 1)
void conv_gemm4(const u16* __restrict__ in, const u16* __restrict__ W,
                const float* __restrict__ scale, const float* __restrict__ shift,
                u16* __restrict__ out, int Hi, int Wi, int Ho, int Wo, int npix)
{
    constexpr int KT = TAPS * 256;
    constexpr int NT = KT / 64;           // K-tiles (36 for TAPS=9)
    static_assert(NT >= 2, "pipeline needs >=2 K-tiles");
    const int HoWo = Ho * Wo;

    __shared__ u16 ldsbuf[65536];         // 128 KB: slot*32768 | A 16384 | B 16384

    const int tid  = threadIdx.x;
    // ---- bijective XCD-aware block swizzle
    const int jt0  = blockIdx.x;
    const int nwg  = gridDim.x;
    const int q8   = nwg >> 3, r8 = nwg & 7;
    const int xcd  = jt0 & 7, sidx = jt0 >> 3;
    const int jt   = (xcd < r8 ? xcd * (q8 + 1)
                               : r8 * (q8 + 1) + (xcd - r8) * q8) + sidx;

    const int wv   = tid >> 6;            // wave 0..3
    const int lane = tid & 63;
    const int wm   = wv >> 1;             // A half
    const int wn   = wv & 1;              // B half
    const int lr   = lane & 15;
    const int lq   = lane >> 4;

    // ---- staging coords: 256 threads cover 32 rows x 8 chunks per round
    const int c8  = tid & 7;
    const int rr  = tid >> 3;             // 0..31
    const int csw = (c8 ^ (rr & 7)) * 8;  // swizzled chunk (u16 units)

    const u16* gA0 = W + (size_t)rr * KT + csw;

    // B pixel pointers: pixel = jt*256 + hq*32 + rr
    const u16* gB[8];
    #pragma unroll
    for (int hq = 0; hq < 8; hq++) {
        int jg = jt * 256 + hq * 32 + rr;
        if (jg >= npix) jg = npix - 1;
        int bb  = jg / HoWo;
        int msp = jg - bb * HoWo;
        int oy  = msp / Wo;
        int ox  = msp - oy * Wo;
        gB[hq] = in + ((size_t)((bb * Hi + oy) * Wi + ox)) * 256 + csw;
    }

    #define STA(slot_, h_, j_) do { if ((j_) < NT) {                          \
        const size_t _ao = (size_t)(j_) * 64;                                 \
        u16* _d = ldsbuf + (slot_) * 32768 + (h_) * 8192 + wv * 512;          \
        gld_lds16(gA0 + (size_t)((h_) * 128 +  0) * KT + _ao, _d);            \
        gld_lds16(gA0 + (size_t)((h_) * 128 + 32) * KT + _ao, _d + 2048);     \
        gld_lds16(gA0 + (size_t)((h_) * 128 + 64) * KT + _ao, _d + 4096);     \
        gld_lds16(gA0 + (size_t)((h_) * 128 + 96) * KT + _ao, _d + 6144);     \
    } } while (0)

    #define STB(slot_, h_, j_) do { if ((j_) < NT) {                          \
        int _ky = 0, _kx = 0;                                                 \
        if (TAPS == 9) { int _t = (j_) >> 2; _ky = _t / 3; _kx = _t - _ky*3; }\
        const int _bo = (_ky * Wi + _kx) * 256 + ((j_) & 3) * 64;             \
        u16* _d = ldsbuf + (slot_) * 32768 + 16384 + (h_) * 8192 + wv * 512;  \
        gld_lds16(gB[(h_) * 4 + 0] + _bo, _d);                                \
        gld_lds16(gB[(h_) * 4 + 1] + _bo, _d + 2048);                         \
        gld_lds16(gB[(h_) * 4 + 2] + _bo, _d + 4096);                         \
        gld_lds16(gB[(h_) * 4 + 3] + _bo, _d + 6144);                         \
    } } while (0)

    #define DSA(DST, RQ) do {                                                 \
        _Pragma("unroll")                                                     \
        for (int ks = 0; ks < 2; ks++) {                                      \
            const int _cx = ks ? x1 : x0;                                     \
            _Pragma("unroll")                                                 \
            for (int f = 0; f < 4; f++) {                                     \
                int _ra = wm * 128 + (RQ) * 64 + f * 16 + lr;                 \
                DST[ks][f] = *(const bf16x8*)&ldsbuf[sA + _ra * 64 + _cx];    \
            }                                                                 \
        }                                                                     \
    } while (0)

    #define DSB(DST, CQ) do {                                                 \
        _Pragma("unroll")                                                     \
        for (int ks = 0; ks < 2; ks++) {                                      \
            const int _cx = ks ? x1 : x0;                                     \
            _Pragma("unroll")                                                 \
            for (int g = 0; g < 4; g++) {                                     \
                int _rb = wn * 128 + (CQ) * 64 + g * 16 + lr;                 \
                DST[ks][g] = *(const bf16x8*)&ldsbuf[sB + _rb * 64 + _cx];    \
            }                                                                 \
        }                                                                     \
    } while (0)

    #define MFMA32(AF, BF, RO, CO) do {                                       \
        __builtin_amdgcn_s_setprio(1);                                        \
        _Pragma("unroll")                                                     \
        for (int ks = 0; ks < 2; ks++)                                        \
            _Pragma("unroll")                                                 \
            for (int f = 0; f < 4; f++)                                       \
                _Pragma("unroll")                                             \
                for (int g = 0; g < 4; g++)                                   \
                    acc[(RO) + f][(CO) + g] =                                 \
                        __builtin_amdgcn_mfma_f32_16x16x32_bf16(              \
                            AF[ks][f], BF[ks][g], acc[(RO) + f][(CO) + g],    \
                            0, 0, 0);                                         \
        __builtin_amdgcn_s_setprio(0);                                        \
    } while (0)

    f32x4 acc[8][8];
    #pragma unroll
    for (int a = 0; a < 8; a++)
        #pragma unroll
        for (int b = 0; b < 8; b++)
            acc[a][b] = (f32x4){0.f, 0.f, 0.f, 0.f};

    const int x0 = ((0 * 4 + lq) ^ (lr & 7)) * 8;
    const int x1 = ((1 * 4 + lq) ^ (lr & 7)) * 8;

    // ---- prologue: tile0 complete + tile1 h0 in flight
    STA(0, 0, 0); STB(0, 0, 0); STA(0, 1, 0); STB(0, 1, 0);
    STB(1, 0, 1); STA(1, 0, 1);
    asm volatile("s_waitcnt vmcnt(8)" ::: "memory");
    __builtin_amdgcn_s_barrier();

    for (int j = 0; j < NT; j++) {
        const int slot = j & 1;
        const int nsl  = slot ^ 1;
        const int sA   = slot * 32768;
        const int sB   = sA + 16384;
        bf16x8 aF[2][4], aG[2][4], bF0[2][4], bF1[2][4];

        // issue all frag reads (in-order: a0, b0, b1, a1) + j+1 h1 stages
        DSA(aF, 0); DSB(bF0, 0); DSB(bF1, 1); DSA(aG, 1);
        STA(nsl, 1, j + 1);
        STB(nsl, 1, j + 1);

        // phase 0: quadrant (0,0) — needs a0 + b0 (first 16 reads; 15 = max
        // encodable lgkmcnt, waits for 17 of 32 — strictly sufficient)
        asm volatile("s_waitcnt lgkmcnt(15)" ::: "memory");
        __builtin_amdgcn_sched_barrier(0);
        MFMA32(aF, bF0, 0, 0);

        // phase 1: quadrant (0,1) — needs b1
        asm volatile("s_waitcnt lgkmcnt(8)" ::: "memory");
        __builtin_amdgcn_sched_barrier(0);
        MFMA32(aF, bF1, 0, 4);
        __builtin_amdgcn_s_barrier();            // B2: all B-slot reads done

        // phase 2: quadrant (1,0) — needs a1; B-slot now safe to overwrite
        STB(slot, 0, j + 2);
        asm volatile("s_waitcnt lgkmcnt(0)" ::: "memory");
        __builtin_amdgcn_sched_barrier(0);
        MFMA32(aG, bF0, 4, 0);
        __builtin_amdgcn_s_barrier();            // B3: all A-slot reads done

        // phase 3: quadrant (1,1); A-slot safe to overwrite
        STA(slot, 0, j + 2);
        MFMA32(aG, bF1, 4, 4);
        if (j + 2 < NT) asm volatile("s_waitcnt vmcnt(8)" ::: "memory");
        else            asm volatile("s_waitcnt vmcnt(0)" ::: "memory");
        __builtin_amdgcn_s_barrier();            // B4: tile j+1 staged
    }

    #undef STA
    #undef STB
    #undef DSA
    #undef DSB
    #undef MFMA32

    // ---- epilogue: BN scale/shift + ReLU, NHWC bf16
    const int obase = jt * 256;
    #pragma unroll
    for (int fr = 0; fr < 8; fr++) {
        const int rb = wm * 128 + fr * 16 + lq * 4;
        const f32x4 sc = *(const f32x4*)&scale[rb];
        const f32x4 sh = *(const f32x4*)&shift[rb];
        #pragma unroll
        for (int fc = 0; fc < 8; fc++) {
            const int jc = obase + wn * 128 + fc * 16 + lr;
            if (jc < npix) {
                Pack4 pk;
                #pragma unroll
                for (int reg = 0; reg < 4; reg++) {
                    float v = acc[fr][fc][reg] * sc[reg] + sh[reg];
                    v = fmaxf(v, 0.f);
                    pk.u[reg] = f2bf(v);
                }
                *(uint2*)&out[(size_t)jc * 256 + rb] = pk.v2;
            }
        }
    }
}

// ---------------------------------------------------------------------------
// Depthwise xcorr, NHWC, oy-grouped for row reuse:
// block = (b, og), og = group of 5 output rows. Reads rows og*5..og*5+8 once
// (9 rows) instead of 5 rows per single oy (25 row-reads per 5 oy) -> 2.8x
// less read traffic. All acc/kf/row indices compile-time (full unroll).
// ---------------------------------------------------------------------------
__global__ __launch_bounds__(256)
void xcorr_kernel(const u16* __restrict__ s, const u16* __restrict__ k,
                  u16* __restrict__ out)
{
    const int b  = blockIdx.x / 5;
    const int og = blockIdx.x - b * 5;     // oy = og*5 + o, o in 0..4
    const int c  = threadIdx.x;

    float kf[25];
    #pragma unroll
    for (int t = 0; t < 25; t++)
        kf[t] = bf2f(k[((size_t)(b * 25 + t)) * 256 + c]);

    float acc[5][25];
    #pragma unroll
    for (int o = 0; o < 5; o++)
        #pragma unroll
        for (int i = 0; i < 25; i++) acc[o][i] = 0.f;

    #pragma unroll
    for (int r = 0; r < 9; r++) {          // absolute row = og*5 + r
        float row[29];
        const u16* sp = s + ((size_t)(b * 29 + og * 5 + r) * 29) * 256 + c;
        #pragma unroll
        for (int x = 0; x < 29; x++) row[x] = bf2f(sp[(size_t)x * 256]);
        #pragma unroll
        for (int dy = 0; dy < 5; dy++) {
            const int o = r - dy;          // compile-time
            if (o >= 0 && o < 5) {
                #pragma unroll
                for (int dx = 0; dx < 5; dx++) {
                    float kv = kf[dy * 5 + dx];
                    #pragma unroll
                    for (int ox = 0; ox < 25; ox++)
                        acc[o][ox] += row[ox + dx] * kv;
                }
            }
        }
    }
    #pragma unroll
    for (int o = 0; o < 5; o++) {
        u16* op = out + ((size_t)(b * 25 + og * 5 + o) * 25) * 256 + c;
        #pragma unroll
        for (int ox = 0; ox < 25; ox++)
            op[(size_t)ox * 256] = f2bf(acc[o][ox]);
    }
}

// ---------------------------------------------------------------------------
// Merged weight/BN prep (one launch)
// ---------------------------------------------------------------------------
__global__ __launch_bounds__(256)
void prep_all(const float* __restrict__ wk, const float* __restrict__ wsw,
              const float* __restrict__ wh1, const float* __restrict__ wh2,
              const float* gk, const float* bk, const float* mk, const float* vk,
              const float* gs, const float* bs, const float* ms, const float* vs,
              const float* gh, const float* bh, const float* mh, const float* vh,
              const float* bh2,
              u16* __restrict__ Wk2, u16* __restrict__ Ws2,
              u16* __restrict__ Wh1b, u16* __restrict__ Wh2b,
              float* sk, float* tk, float* ss, float* ts,
              float* sh, float* th, float* s5, float* t5)
{
    int blk = blockIdx.x;
    int tidx = threadIdx.x;
    if (blk < 4608) {
        const float* w = (blk < 2304) ? wk : wsw;
        u16* o = (blk < 2304) ? Wk2 : Ws2;
        int idx = (blk % 2304) * 256 + tidx;
        int oc = idx / 2304, rem = idx - oc * 2304;
        int tap = rem >> 8, c = rem & 255;
        o[idx] = f2bf(w[oc * 2304 + c * 9 + tap]);
    } else if (blk < 5120) {
        const float* w = (blk < 4864) ? wh1 : wh2;
        u16* o = (blk < 4864) ? Wh1b : Wh2b;
        int idx = ((blk - 4608) % 256) * 256 + tidx;
        o[idx] = f2bf(w[idx]);
    } else {
        int i = tidx;
        float iv;
        iv = rsqrtf(vk[i] + EPS_BN) * gk[i]; sk[i] = iv; tk[i] = bk[i] - mk[i] * iv;
        iv = rsqrtf(vs[i] + EPS_BN) * gs[i]; ss[i] = iv; ts[i] = bs[i] - ms[i] * iv;
        iv = rsqrtf(vh[i] + EPS_BN) * gh[i]; sh[i] = iv; th[i] = bh[i] - mh[i] * iv;
        s5[i] = 1.f; t5[i] = bh2[i];
    }
}

// ---------------------------------------------------------------------------
extern "C" void kernel_launch(void* const* d_in, const int* in_sizes, int n_in,
                              void* d_out, int out_size, void* d_ws, size_t ws_size,
                              hipStream_t stream)
{
    const float* in_kernel = (const float*)d_in[0];
    const float* in_search = (const float*)d_in[1];
    const float* wk  = (const float*)d_in[2];
    const float* gk  = (const float*)d_in[3];
    const float* bk  = (const float*)d_in[4];
    const float* mk  = (const float*)d_in[5];
    const float* vk  = (const float*)d_in[6];
    const float* wsw = (const float*)d_in[7];
    const float* gs  = (const float*)d_in[8];
    const float* bs  = (const float*)d_in[9];
    const float* ms  = (const float*)d_in[10];
    const float* vs  = (const float*)d_in[11];
    const float* wh1 = (const float*)d_in[12];
    const float* gh  = (const float*)d_in[13];
    const float* bh  = (const float*)d_in[14];
    const float* mh  = (const float*)d_in[15];
    const float* vh  = (const float*)d_in[16];
    const float* wh2 = (const float*)d_in[17];
    const float* bh2 = (const float*)d_in[18];
    float* out = (float*)d_out;

    char* w = (char*)d_ws;
    u16* Wk2 = (u16*)w;  w += 1179648;      // 256*2304 bf16
    u16* Ws2 = (u16*)w;  w += 1179648;
    u16* Wh1 = (u16*)w;  w += 131072;       // 256*256 bf16
    u16* Wh2 = (u16*)w;  w += 131072;
    float* sk = (float*)w; w += 1024;
    float* tk = (float*)w; w += 1024;
    float* ss = (float*)w; w += 1024;
    float* ts = (float*)w; w += 1024;
    float* sh = (float*)w; w += 1024;
    float* th = (float*)w; w += 1024;
    float* s5 = (float*)w; w += 1024;
    float* t5 = (float*)w; w += 1024;
    u16* kfeat = (u16*)w; w += 1638400;     // 128*25*256 bf16
    u16* sfeat = (u16*)w; w += 55115776;    // 128*841*256 bf16
    u16* feat  = (u16*)w; w += 40960000;    // 128*625*256 bf16
    u16* ktr   = (u16*)w; w += 3211264;     // 128*49*256 bf16 (NHWC kernel input)
    u16* strA  = (u16*)w; w += 62980096;    // 128*961*256 bf16 (NHWC search input)
    u16* hbuf  = strA;                      // alias: strA dead after stage 2

    tr_all<<<2048 + 128, 256, 0, stream>>>(in_search, in_kernel, strA, ktr);
    prep_all<<<5121, 256, 0, stream>>>(wk, wsw, wh1, wh2,
                                       gk, bk, mk, vk, gs, bs, ms, vs,
                                       gh, bh, mh, vh, bh2,
                                       Wk2, Ws2, Wh1, Wh2,
                                       sk, tk, ss, ts, sh, th, s5, t5);

    // stage 1: kernel tower  -> kfeat NHWC [128*25, 256]
    conv_gemm<9, true, u16, true><<<dim3(2, 25), 256, 0, stream>>>(
        ktr, Wk2, sk, tk, kfeat, 7, 7, 5, 5);
    // stage 2: search tower  -> sfeat NHWC [128*841, 256]
    //   256x256 tile, 4 waves x 128x128, LDS-traffic-reduced pipeline.
    conv_gemm4<9><<<dim3(421), 256, 0, stream>>>(
        strA, Ws2, ss, ts, sfeat, 31, 31, 29, 29, 128 * 841);
    // stage 3: depthwise xcorr -> feat NHWC [128*625, 256]
    xcorr_kernel<<<128 * 5, 256, 0, stream>>>(sfeat, kfeat, feat);
    // stage 4: head 1x1 + BN + ReLU -> hbuf NHWC
    conv_gemm<1, true, u16, true><<<dim3(2, 625), 256, 0, stream>>>(
        feat, Wh1, sh, th, hbuf, 25, 25, 25, 25);
    // stage 5: head 1x1 + bias -> out NCHW fp32
    conv_gemm<1, false, float, false><<<dim3(2, 625), 256, 0, stream>>>(
        hbuf, Wh2, s5, t5, out, 25, 25, 25, 25);

    (void)in_sizes; (void)n_in; (void)out_size; (void)ws_size;
}

// Round 7
// 524.331 us; speedup vs baseline: 1.1278x; 1.1278x over previous
//
#include <hip/hip_runtime.h>
#include <hip/hip_bf16.h>
#include <cstdint>
#include <cstddef>

typedef unsigned short u16;
typedef __attribute__((ext_vector_type(8))) __bf16 bf16x8;
typedef __attribute__((ext_vector_type(4))) float f32x4;

#define EPS_BN 1e-5f

__device__ __forceinline__ u16 f2bf(float f) {
    union { float f; uint32_t u; } v; v.f = f;
    uint32_t u = v.u;
    u += 0x7FFFu + ((u >> 16) & 1u);   // round-to-nearest-even
    return (u16)(u >> 16);
}
__device__ __forceinline__ float bf2f(u16 s) {
    union { uint32_t u; float f; } v; v.u = ((uint32_t)s) << 16;
    return v.f;
}

union Pack8 { u16 u[8]; uint4 v4; };
union Pack4 { u16 u[4]; uint2 v2; };

// async global -> LDS, 16B per lane; LDS dest = wave-uniform base + lane*16
typedef __attribute__((address_space(1))) const unsigned char as1c;
typedef __attribute__((address_space(3))) unsigned char as3;
__device__ __forceinline__ void gld_lds16(const void* g, void* l) {
    __builtin_amdgcn_global_load_lds((as1c*)g, (as3*)l, 16, 0, 0);
}

// ---------------------------------------------------------------------------
// Transpose NCHW fp32 -> NHWC bf16 via LDS tile. (round-5 version, kept)
// ---------------------------------------------------------------------------
__device__ __forceinline__ void tr_tile(const float* __restrict__ in,
                                        u16* __restrict__ out,
                                        int P, int b, int p0)
{
    __shared__ u16 t_lds[64 * 256];        // 32 KB
    const int tid = threadIdx.x;
    const int w  = tid >> 6;               // wave: channel block w*64
    const int ln = tid & 63;               // lane: pixel p0+ln

    {
        const int p  = p0 + ln;
        const int pc = (p < P) ? p : (P - 1);   // clamp read, store guarded
        const float* ib = in + ((size_t)b * 256 + w * 64) * P + pc;
        #pragma unroll
        for (int k = 0; k < 8; k++) {
            Pack8 pk;
            #pragma unroll
            for (int i = 0; i < 8; i++)
                pk.u[i] = f2bf(ib[(size_t)(k * 8 + i) * P]);
            const int chunk = w * 8 + k;        // 16B chunk 0..31
            *(uint4*)&t_lds[ln * 256 + ((chunk ^ (ln & 31)) * 8)] = pk.v4;
        }
    }
    __syncthreads();
    {
        const int ch = tid & 31;               // chunk
        const int pg = tid >> 5;               // 0..7
        #pragma unroll
        for (int it = 0; it < 8; it++) {
            int px = it * 8 + pg;
            int p  = p0 + px;
            uint4 v = *(const uint4*)&t_lds[px * 256 + ((ch ^ (px & 31)) * 8)];
            if (p < P)
                *(uint4*)(out + ((size_t)(b * P + p)) * 256 + ch * 8) = v;
        }
    }
}

__global__ __launch_bounds__(256)
void tr_all(const float* __restrict__ s, const float* __restrict__ k,
            u16* __restrict__ so, u16* __restrict__ ko)
{
    int blk = blockIdx.x;
    if (blk < 2048) {
        tr_tile(s, so, 961, blk >> 4, (blk & 15) * 64);
    } else {
        tr_tile(k, ko, 49, blk - 2048, 0);
    }
}

// ---------------------------------------------------------------------------
// Implicit-im2col GEMM, NHWC bf16 input (old 128x128 / 4-wave structure).
// Kept for stage 1 only (tiny grid).
// ---------------------------------------------------------------------------
template<int TAPS, bool NHWC_OUT, typename OutT, bool RELU>
__global__ __launch_bounds__(256)
void conv_gemm(const u16* __restrict__ in, const u16* __restrict__ W,
               const float* __restrict__ scale, const float* __restrict__ shift,
               OutT* __restrict__ out, int Hi, int Wi, int Ho, int Wo)
{
    constexpr int KT = TAPS * 256;
    constexpr int KB = KT / 64;
    const int HoWo = Ho * Wo;

    __shared__ u16 Alds[8192];
    __shared__ u16 Blds[8192];

    const int tid = threadIdx.x;
    const int it = blockIdx.x;
    const int jt = blockIdx.y;
    const int wv = tid >> 6;
    const int lane = tid & 63;

    const int c8 = tid & 7;
    const int t3 = tid >> 3;
    const int csw = c8 ^ (t3 & 7);

    const u16* gA[4];
    const u16* gB[4];
    #pragma unroll
    for (int q = 0; q < 4; q++) {
        int r = q * 32 + t3;
        gA[q] = W + (size_t)(it * 128 + r) * KT + csw * 8;
        int jg = jt * 128 + r;
        int bb = jg / HoWo;
        int msp = jg - bb * HoWo;
        int oyp = msp / Wo;
        int oxp = msp - oyp * Wo;
        gB[q] = in + ((size_t)(bb * Hi + oyp) * Wi + oxp) * 256 + csw * 8;
    }

    const int wi = (wv >> 1) * 64;
    const int wj = (wv & 1) * 64;
    const int lr = lane & 15;
    const int lq = lane >> 4;

    f32x4 acc[4][4];
    #pragma unroll
    for (int a = 0; a < 4; a++)
        #pragma unroll
        for (int b = 0; b < 4; b++)
            acc[a][b] = (f32x4){0.f, 0.f, 0.f, 0.f};

    for (int kb = 0; kb < KB; kb++) {
        const int tap = (TAPS == 1) ? 0 : (kb >> 2);
        const int c0  = (TAPS == 1) ? (kb * 64) : ((kb & 3) * 64);
        int ky = 0, kx = 0;
        if (TAPS == 9) { ky = tap / 3; kx = tap - ky * 3; }
        const int aoff = tap * 256 + c0;
        const int boff = (ky * Wi + kx) * 256 + c0;
        __syncthreads();
        #pragma unroll
        for (int q = 0; q < 4; q++)
            gld_lds16(gA[q] + aoff, Alds + q * 2048 + wv * 512);
        #pragma unroll
        for (int q = 0; q < 4; q++)
            gld_lds16(gB[q] + boff, Blds + q * 2048 + wv * 512);
        __syncthreads();
        #pragma unroll
        for (int ks = 0; ks < 2; ks++) {
            bf16x8 af[4], bfr[4];
            const int ck = ks * 4 + lq;
            #pragma unroll
            for (int f = 0; f < 4; f++) {
                int ra = wi + f * 16 + lr;
                af[f]  = *(const bf16x8*)&Alds[ra * 64 + ((ck ^ (ra & 7)) * 8)];
                int rb = wj + f * 16 + lr;
                bfr[f] = *(const bf16x8*)&Blds[rb * 64 + ((ck ^ (rb & 7)) * 8)];
            }
            #pragma unroll
            for (int fi = 0; fi < 4; fi++)
                #pragma unroll
                for (int fj = 0; fj < 4; fj++)
                    acc[fi][fj] = __builtin_amdgcn_mfma_f32_16x16x32_bf16(
                        af[fi], bfr[fj], acc[fi][fj], 0, 0, 0);
        }
    }

    if constexpr (NHWC_OUT) {
        int jc[4];
        #pragma unroll
        for (int fj = 0; fj < 4; fj++) jc[fj] = jt * 128 + wj + fj * 16 + lr;
        #pragma unroll
        for (int fi = 0; fi < 4; fi++) {
            int rb = it * 128 + wi + fi * 16 + lq * 4;
            f32x4 sc = *(const f32x4*)&scale[rb];
            f32x4 sh = *(const f32x4*)&shift[rb];
            #pragma unroll
            for (int fj = 0; fj < 4; fj++) {
                Pack4 pk;
                #pragma unroll
                for (int reg = 0; reg < 4; reg++) {
                    float v = acc[fi][fj][reg] * sc[reg] + sh[reg];
                    if (RELU) v = fmaxf(v, 0.f);
                    pk.u[reg] = f2bf(v);
                }
                *(uint2*)&((u16*)out)[(size_t)jc[fj] * 256 + rb] = pk.v2;
            }
        }
    } else {
        int jcb[4], jcm[4];
        #pragma unroll
        for (int fj = 0; fj < 4; fj++) {
            int jc = jt * 128 + wj + fj * 16 + lr;
            int b = jc / HoWo;
            jcb[fj] = b; jcm[fj] = jc - b * HoWo;
        }
        #pragma unroll
        for (int fi = 0; fi < 4; fi++) {
            int rb = it * 128 + wi + fi * 16 + lq * 4;
            f32x4 sc = *(const f32x4*)&scale[rb];
            f32x4 sh = *(const f32x4*)&shift[rb];
            #pragma unroll
            for (int reg = 0; reg < 4; reg++) {
                int r = rb + reg;
                #pragma unroll
                for (int fj = 0; fj < 4; fj++) {
                    float v = acc[fi][fj][reg] * sc[reg] + sh[reg];
                    if (RELU) v = fmaxf(v, 0.f);
                    size_t o = ((size_t)(jcb[fj] * 256 + r)) * HoWo + jcm[fj];
                    ((float*)out)[o] = v;
                }
            }
        }
    }
}

// ---------------------------------------------------------------------------
// 256x256-tile 8-phase pipelined implicit-im2col GEMM (stage 2).
// Round-3 version (measured 157 us): 8 waves (2M x 4N), per-wave 128x64,
// counted vmcnt(4), XCD-swizzled jt.
// ---------------------------------------------------------------------------
template<int TAPS>
__global__ __launch_bounds__(512, 2)
void conv_gemm8(const u16* __restrict__ in, const u16* __restrict__ W,
                const float* __restrict__ scale, const float* __restrict__ shift,
                u16* __restrict__ out, int Hi, int Wi, int Ho, int Wo, int npix)
{
    constexpr int KT = TAPS * 256;
    constexpr int NT = KT / 64;           // K-tiles (36 for TAPS=9)
    static_assert(NT >= 2, "pipeline needs >=2 K-tiles");
    const int HoWo = Ho * Wo;

    __shared__ u16 ldsbuf[65536];         // 128 KB

    const int tid  = threadIdx.x;
    // ---- bijective XCD-aware block swizzle
    const int jt0  = blockIdx.x;
    const int nwg  = gridDim.x;
    const int q8   = nwg >> 3, r8 = nwg & 7;
    const int xcd  = jt0 & 7, sidx = jt0 >> 3;
    const int jt   = (xcd < r8 ? xcd * (q8 + 1)
                               : r8 * (q8 + 1) + (xcd - r8) * q8) + sidx;
    const int wv   = tid >> 6;            // wave 0..7
    const int lane = tid & 63;
    const int wm   = wv >> 2;             // 0..1 : A rows half
    const int wn   = wv & 3;              // 0..3 : B cols quarter
    const int lr   = lane & 15;
    const int lq   = lane >> 4;

    const int c8  = tid & 7;
    const int rr  = tid >> 3;             // 0..63
    const int csw = (c8 ^ (rr & 7)) * 8;  // swizzled global chunk (u16 units)

    const u16* gA00 = W + (size_t)(rr)        * KT + csw;
    const u16* gA01 = W + (size_t)(64  + rr)  * KT + csw;
    const u16* gA10 = W + (size_t)(128 + rr)  * KT + csw;
    const u16* gA11 = W + (size_t)(192 + rr)  * KT + csw;

    const u16* gB00; const u16* gB01; const u16* gB10; const u16* gB11;
    {
        #pragma unroll
        for (int hq = 0; hq < 4; hq++) {
            int jg = jt * 256 + hq * 64 + rr;
            if (jg >= npix) jg = npix - 1;
            int bb  = jg / HoWo;
            int msp = jg - bb * HoWo;
            int oy  = msp / Wo;
            int ox  = msp - oy * Wo;
            const u16* p = in + ((size_t)((bb * Hi + oy) * Wi + ox)) * 256 + csw;
            if (hq == 0) gB00 = p; else if (hq == 1) gB01 = p;
            else if (hq == 2) gB10 = p; else gB11 = p;
        }
    }

    #define STA(slot_, h_, j_) do { if ((j_) < NT) {                          \
        const int _ao = (j_) * 64;                                            \
        u16* _d = ldsbuf + (slot_) * 32768 + (h_) * 8192 + wv * 512;          \
        gld_lds16(((h_) ? gA10 : gA00) + _ao, _d);                            \
        gld_lds16(((h_) ? gA11 : gA01) + _ao, _d + 4096);                     \
    } } while (0)

    #define STB(slot_, h_, j_) do { if ((j_) < NT) {                          \
        int _ky = 0, _kx = 0;                                                 \
        if (TAPS == 9) { int _t = (j_) >> 2; _ky = _t / 3; _kx = _t - _ky*3; }\
        const int _bo = (_ky * Wi + _kx) * 256 + ((j_) & 3) * 64;             \
        u16* _d = ldsbuf + (slot_) * 32768 + 16384 + (h_) * 8192 + wv * 512;  \
        gld_lds16(((h_) ? gB10 : gB00) + _bo, _d);                            \
        gld_lds16(((h_) ? gB11 : gB01) + _bo, _d + 4096);                     \
    } } while (0)

    #define DSA(RQ) do {                                                      \
        _Pragma("unroll")                                                     \
        for (int ks = 0; ks < 2; ks++) {                                      \
            const int _cx = ks ? x1 : x0;                                     \
            _Pragma("unroll")                                                 \
            for (int f = 0; f < 4; f++) {                                     \
                int _ra = wm * 128 + (RQ) * 64 + f * 16 + lr;                 \
                aF[ks][f] = *(const bf16x8*)&ldsbuf[sA + _ra * 64 + _cx];     \
            }                                                                 \
        }                                                                     \
    } while (0)

    #define DSB(BF, CQ) do {                                                  \
        _Pragma("unroll")                                                     \
        for (int ks = 0; ks < 2; ks++) {                                      \
            const int _cx = ks ? x1 : x0;                                     \
            _Pragma("unroll")                                                 \
            for (int g = 0; g < 2; g++) {                                     \
                int _rb = wn * 64 + (CQ) * 32 + g * 16 + lr;                  \
                BF[ks][g] = *(const bf16x8*)&ldsbuf[sB + _rb * 64 + _cx];     \
            }                                                                 \
        }                                                                     \
    } while (0)

    #define MFMA16(AF, BF, RO, CO) do {                                       \
        __builtin_amdgcn_s_setprio(1);                                        \
        _Pragma("unroll")                                                     \
        for (int ks = 0; ks < 2; ks++)                                        \
            _Pragma("unroll")                                                 \
            for (int f = 0; f < 4; f++)                                       \
                _Pragma("unroll")                                             \
                for (int g = 0; g < 2; g++)                                   \
                    acc[(RO) + f][(CO) + g] =                                 \
                        __builtin_amdgcn_mfma_f32_16x16x32_bf16(              \
                            AF[ks][f], BF[ks][g], acc[(RO) + f][(CO) + g],    \
                            0, 0, 0);                                         \
        __builtin_amdgcn_s_setprio(0);                                        \
    } while (0)

    f32x4 acc[8][4];
    #pragma unroll
    for (int a = 0; a < 8; a++)
        #pragma unroll
        for (int b = 0; b < 4; b++)
            acc[a][b] = (f32x4){0.f, 0.f, 0.f, 0.f};

    const int x0 = ((0 * 4 + lq) ^ (lr & 7)) * 8;   // k-chunk offset, ks=0
    const int x1 = ((1 * 4 + lq) ^ (lr & 7)) * 8;   // k-chunk offset, ks=1

    // ---- prologue: tile0 complete + B(1)h0 + A(1)h0 in flight
    STA(0, 0, 0); STA(0, 1, 0); STB(0, 0, 0); STB(0, 1, 0);
    STB(1, 0, 1); STA(1, 0, 1);
    asm volatile("s_waitcnt vmcnt(4)" ::: "memory");
    __builtin_amdgcn_s_barrier();

    for (int j = 0; j < NT; j++) {
        const int slot = j & 1;
        const int nsl  = slot ^ 1;
        const int sA   = slot * 32768;
        const int sB   = sA + 16384;
        bf16x8 aF[2][4], bF0[2][2], bF1[2][2];

        // ---- phase 0: quadrant (r=0, c=0)
        DSA(0); DSB(bF0, 0);
        STA(nsl, 1, j + 1);
        __builtin_amdgcn_s_barrier();
        asm volatile("s_waitcnt lgkmcnt(0)" ::: "memory");
        MFMA16(aF, bF0, 0, 0);
        __builtin_amdgcn_s_barrier();

        // ---- phase 1: quadrant (r=0, c=1)
        DSB(bF1, 1);
        STB(nsl, 1, j + 1);
        __builtin_amdgcn_s_barrier();
        asm volatile("s_waitcnt lgkmcnt(0)" ::: "memory");
        MFMA16(aF, bF1, 0, 2);
        __builtin_amdgcn_s_barrier();

        // ---- phase 2: quadrant (r=1, c=0)  [all B reads of tile j done]
        DSA(1);
        STB(slot, 0, j + 2);
        __builtin_amdgcn_s_barrier();
        asm volatile("s_waitcnt lgkmcnt(0)" ::: "memory");
        MFMA16(aF, bF0, 4, 0);
        __builtin_amdgcn_s_barrier();

        // ---- phase 3: quadrant (r=1, c=1)  [all A reads of tile j done]
        STA(slot, 0, j + 2);
        if (j + 2 < NT) asm volatile("s_waitcnt vmcnt(4)" ::: "memory");
        else            asm volatile("s_waitcnt vmcnt(0)" ::: "memory");
        __builtin_amdgcn_s_barrier();
        MFMA16(aF, bF1, 4, 2);
        __builtin_amdgcn_s_barrier();
    }

    #undef STA
    #undef STB
    #undef DSA
    #undef DSB
    #undef MFMA16

    // ---- epilogue: BN scale/shift + ReLU, NHWC bf16
    const int obase = jt * 256;
    #pragma unroll
    for (int fr = 0; fr < 8; fr++) {
        const int rb = wm * 128 + fr * 16 + lq * 4;
        const f32x4 sc = *(const f32x4*)&scale[rb];
        const f32x4 sh = *(const f32x4*)&shift[rb];
        #pragma unroll
        for (int fc = 0; fc < 4; fc++) {
            const int jc = obase + wn * 64 + fc * 16 + lr;
            if (jc < npix) {
                Pack4 pk;
                #pragma unroll
                for (int reg = 0; reg < 4; reg++) {
                    float v = acc[fr][fc][reg] * sc[reg] + sh[reg];
                    v = fmaxf(v, 0.f);
                    pk.u[reg] = f2bf(v);
                }
                *(uint2*)&out[(size_t)jc * 256 + rb] = pk.v2;
            }
        }
    }
}

// ---------------------------------------------------------------------------
// Fused head: out = (relu(bn(feat@W1^T)))@W2^T + bias, NCHW fp32.
// 512 thr / 8 waves, J-tile = 128 pixels, K=256 both GEMMs (4 tiles of 64).
// GEMM1 -> h kept in LDS (128 x 256 bf16, 16B-chunk ^ (j&31) swizzle);
// GEMM2 reads B-frags straight from Hlds (no global staging for B).
// Removes the 82MB hbuf intermediate write+read and one launch.
// ---------------------------------------------------------------------------
__global__ __launch_bounds__(512)
void head_fused(const u16* __restrict__ feat, const u16* __restrict__ W1,
                const u16* __restrict__ W2,
                const float* __restrict__ scale1, const float* __restrict__ shift1,
                const float* __restrict__ bias2,
                float* __restrict__ out)
{
    __shared__ u16 Alds[16384];   // 32 KB: 256 rows x 64k, chunk ^ (row&7)
    __shared__ u16 Blds[8192];    // 16 KB: 128 rows x 64k
    __shared__ u16 Hlds[32768];   // 64 KB: 128 j x 256 ch, 16B-chunk ^ (j&31)

    const int tid  = threadIdx.x;
    const int jt   = blockIdx.x;
    const int wv   = tid >> 6;
    const int lane = tid & 63;
    const int wm   = wv >> 2;          // oc half
    const int wn   = wv & 3;           // j quarter
    const int lr   = lane & 15;
    const int lq   = lane >> 4;

    const int c8  = tid & 7;
    const int rr  = tid >> 3;          // 0..63
    const int csw = (c8 ^ (rr & 7)) * 8;

    f32x4 acc[8][2];
    #pragma unroll
    for (int f = 0; f < 8; f++)
        #pragma unroll
        for (int g = 0; g < 2; g++)
            acc[f][g] = (f32x4){0.f, 0.f, 0.f, 0.f};

    // ---------------- GEMM1: feat(J128 x K256) @ W1(256 x 256)^T
    for (int kb = 0; kb < 4; kb++) {
        __syncthreads();
        #pragma unroll
        for (int q = 0; q < 4; q++)
            gld_lds16(W1 + (size_t)(q * 64 + rr) * 256 + kb * 64 + csw,
                      Alds + q * 4096 + wv * 512);
        #pragma unroll
        for (int q = 0; q < 2; q++)
            gld_lds16(feat + (size_t)(jt * 128 + q * 64 + rr) * 256 + kb * 64 + csw,
                      Blds + q * 4096 + wv * 512);
        __syncthreads();
        #pragma unroll
        for (int ks = 0; ks < 2; ks++) {
            const int ck = ks * 4 + lq;
            bf16x8 af[8], bf[2];
            #pragma unroll
            for (int f = 0; f < 8; f++) {
                int ra = wm * 128 + f * 16 + lr;
                af[f] = *(const bf16x8*)&Alds[ra * 64 + ((ck ^ (ra & 7)) * 8)];
            }
            #pragma unroll
            for (int g = 0; g < 2; g++) {
                int rb = wn * 32 + g * 16 + lr;
                bf[g] = *(const bf16x8*)&Blds[rb * 64 + ((ck ^ (rb & 7)) * 8)];
            }
            #pragma unroll
            for (int f = 0; f < 8; f++)
                #pragma unroll
                for (int g = 0; g < 2; g++)
                    acc[f][g] = __builtin_amdgcn_mfma_f32_16x16x32_bf16(
                        af[f], bf[g], acc[f][g], 0, 0, 0);
        }
    }

    // ---- epilogue 1: BN + ReLU -> Hlds (swizzled); re-zero acc for GEMM2
    #pragma unroll
    for (int f = 0; f < 8; f++) {
        const int rb = wm * 128 + f * 16 + lq * 4;      // oc base (4 regs)
        const f32x4 sc = *(const f32x4*)&scale1[rb];
        const f32x4 sf = *(const f32x4*)&shift1[rb];
        #pragma unroll
        for (int g = 0; g < 2; g++) {
            const int j = wn * 32 + g * 16 + lr;
            Pack4 pk;
            #pragma unroll
            for (int r = 0; r < 4; r++) {
                float v = acc[f][g][r] * sc[r] + sf[r];
                v = fmaxf(v, 0.f);
                pk.u[r] = f2bf(v);
            }
            const int ch = rb >> 3;                     // 16B chunk 0..31
            *(uint2*)&Hlds[j * 256 + ((ch ^ (j & 31)) * 8) + (rb & 7)] = pk.v2;
            acc[f][g] = (f32x4){0.f, 0.f, 0.f, 0.f};
        }
    }

    // ---------------- GEMM2: h(J128 x K256) @ W2(256 x 256)^T
    for (int kb = 0; kb < 4; kb++) {
        __syncthreads();   // kb=0: Hlds writes visible; all: prev Alds reads done
        #pragma unroll
        for (int q = 0; q < 4; q++)
            gld_lds16(W2 + (size_t)(q * 64 + rr) * 256 + kb * 64 + csw,
                      Alds + q * 4096 + wv * 512);
        __syncthreads();
        #pragma unroll
        for (int ks = 0; ks < 2; ks++) {
            const int ck = ks * 4 + lq;
            const int ch32 = kb * 8 + ck;               // 16B chunk in h row
            bf16x8 af[8], bf[2];
            #pragma unroll
            for (int f = 0; f < 8; f++) {
                int ra = wm * 128 + f * 16 + lr;
                af[f] = *(const bf16x8*)&Alds[ra * 64 + ((ck ^ (ra & 7)) * 8)];
            }
            #pragma unroll
            for (int g = 0; g < 2; g++) {
                int j = wn * 32 + g * 16 + lr;
                bf[g] = *(const bf16x8*)&Hlds[j * 256 + ((ch32 ^ (j & 31)) * 8)];
            }
            #pragma unroll
            for (int f = 0; f < 8; f++)
                #pragma unroll
                for (int g = 0; g < 2; g++)
                    acc[f][g] = __builtin_amdgcn_mfma_f32_16x16x32_bf16(
                        af[f], bf[g], acc[f][g], 0, 0, 0);
        }
    }

    // ---- epilogue 2: + bias, NCHW fp32 (HoWo = 625, 128*625 = 80000 exact)
    #pragma unroll
    for (int f = 0; f < 8; f++) {
        const int oc = wm * 128 + f * 16 + lq * 4;
        const f32x4 b2 = *(const f32x4*)&bias2[oc];
        #pragma unroll
        for (int g = 0; g < 2; g++) {
            const int j  = jt * 128 + wn * 32 + g * 16 + lr;
            const int bb = j / 625;
            const int pix = j - bb * 625;
            #pragma unroll
            for (int r = 0; r < 4; r++)
                out[((size_t)(bb * 256 + oc + r)) * 625 + pix] = acc[f][g][r] + b2[r];
        }
    }
}

// ---------------------------------------------------------------------------
// Depthwise xcorr, NHWC, oy-grouped (round-5 version, kept)
// ---------------------------------------------------------------------------
__global__ __launch_bounds__(256)
void xcorr_kernel(const u16* __restrict__ s, const u16* __restrict__ k,
                  u16* __restrict__ out)
{
    const int b  = blockIdx.x / 5;
    const int og = blockIdx.x - b * 5;     // oy = og*5 + o, o in 0..4
    const int c  = threadIdx.x;

    float kf[25];
    #pragma unroll
    for (int t = 0; t < 25; t++)
        kf[t] = bf2f(k[((size_t)(b * 25 + t)) * 256 + c]);

    float acc[5][25];
    #pragma unroll
    for (int o = 0; o < 5; o++)
        #pragma unroll
        for (int i = 0; i < 25; i++) acc[o][i] = 0.f;

    #pragma unroll
    for (int r = 0; r < 9; r++) {          // absolute row = og*5 + r
        float row[29];
        const u16* sp = s + ((size_t)(b * 29 + og * 5 + r) * 29) * 256 + c;
        #pragma unroll
        for (int x = 0; x < 29; x++) row[x] = bf2f(sp[(size_t)x * 256]);
        #pragma unroll
        for (int dy = 0; dy < 5; dy++) {
            const int o = r - dy;          // compile-time
            if (o >= 0 && o < 5) {
                #pragma unroll
                for (int dx = 0; dx < 5; dx++) {
                    float kv = kf[dy * 5 + dx];
                    #pragma unroll
                    for (int ox = 0; ox < 25; ox++)
                        acc[o][ox] += row[ox + dx] * kv;
                }
            }
        }
    }
    #pragma unroll
    for (int o = 0; o < 5; o++) {
        u16* op = out + ((size_t)(b * 25 + og * 5 + o) * 25) * 256 + c;
        #pragma unroll
        for (int ox = 0; ox < 25; ox++)
            op[(size_t)ox * 256] = f2bf(acc[o][ox]);
    }
}

// ---------------------------------------------------------------------------
// Merged weight/BN prep (one launch)
// ---------------------------------------------------------------------------
__global__ __launch_bounds__(256)
void prep_all(const float* __restrict__ wk, const float* __restrict__ wsw,
              const float* __restrict__ wh1, const float* __restrict__ wh2,
              const float* gk, const float* bk, const float* mk, const float* vk,
              const float* gs, const float* bs, const float* ms, const float* vs,
              const float* gh, const float* bh, const float* mh, const float* vh,
              const float* bh2,
              u16* __restrict__ Wk2, u16* __restrict__ Ws2,
              u16* __restrict__ Wh1b, u16* __restrict__ Wh2b,
              float* sk, float* tk, float* ss, float* ts,
              float* sh, float* th, float* s5, float* t5)
{
    int blk = blockIdx.x;
    int tidx = threadIdx.x;
    if (blk < 4608) {
        const float* w = (blk < 2304) ? wk : wsw;
        u16* o = (blk < 2304) ? Wk2 : Ws2;
        int idx = (blk % 2304) * 256 + tidx;
        int oc = idx / 2304, rem = idx - oc * 2304;
        int tap = rem >> 8, c = rem & 255;
        o[idx] = f2bf(w[oc * 2304 + c * 9 + tap]);
    } else if (blk < 5120) {
        const float* w = (blk < 4864) ? wh1 : wh2;
        u16* o = (blk < 4864) ? Wh1b : Wh2b;
        int idx = ((blk - 4608) % 256) * 256 + tidx;
        o[idx] = f2bf(w[idx]);
    } else {
        int i = tidx;
        float iv;
        iv = rsqrtf(vk[i] + EPS_BN) * gk[i]; sk[i] = iv; tk[i] = bk[i] - mk[i] * iv;
        iv = rsqrtf(vs[i] + EPS_BN) * gs[i]; ss[i] = iv; ts[i] = bs[i] - ms[i] * iv;
        iv = rsqrtf(vh[i] + EPS_BN) * gh[i]; sh[i] = iv; th[i] = bh[i] - mh[i] * iv;
        s5[i] = 1.f; t5[i] = bh2[i];
    }
}

// ---------------------------------------------------------------------------
extern "C" void kernel_launch(void* const* d_in, const int* in_sizes, int n_in,
                              void* d_out, int out_size, void* d_ws, size_t ws_size,
                              hipStream_t stream)
{
    const float* in_kernel = (const float*)d_in[0];
    const float* in_search = (const float*)d_in[1];
    const float* wk  = (const float*)d_in[2];
    const float* gk  = (const float*)d_in[3];
    const float* bk  = (const float*)d_in[4];
    const float* mk  = (const float*)d_in[5];
    const float* vk  = (const float*)d_in[6];
    const float* wsw = (const float*)d_in[7];
    const float* gs  = (const float*)d_in[8];
    const float* bs  = (const float*)d_in[9];
    const float* ms  = (const float*)d_in[10];
    const float* vs  = (const float*)d_in[11];
    const float* wh1 = (const float*)d_in[12];
    const float* gh  = (const float*)d_in[13];
    const float* bh  = (const float*)d_in[14];
    const float* mh  = (const float*)d_in[15];
    const float* vh  = (const float*)d_in[16];
    const float* wh2 = (const float*)d_in[17];
    const float* bh2 = (const float*)d_in[18];
    float* out = (float*)d_out;

    char* w = (char*)d_ws;
    u16* Wk2 = (u16*)w;  w += 1179648;      // 256*2304 bf16
    u16* Ws2 = (u16*)w;  w += 1179648;
    u16* Wh1 = (u16*)w;  w += 131072;       // 256*256 bf16
    u16* Wh2 = (u16*)w;  w += 131072;
    float* sk = (float*)w; w += 1024;
    float* tk = (float*)w; w += 1024;
    float* ss = (float*)w; w += 1024;
    float* ts = (float*)w; w += 1024;
    float* sh = (float*)w; w += 1024;
    float* th = (float*)w; w += 1024;
    float* s5 = (float*)w; w += 1024;
    float* t5 = (float*)w; w += 1024;
    u16* kfeat = (u16*)w; w += 1638400;     // 128*25*256 bf16
    u16* sfeat = (u16*)w; w += 55115776;    // 128*841*256 bf16
    u16* feat  = (u16*)w; w += 40960000;    // 128*625*256 bf16
    u16* ktr   = (u16*)w; w += 3211264;     // 128*49*256 bf16 (NHWC kernel input)
    u16* strA  = (u16*)w; w += 62980096;    // 128*961*256 bf16 (NHWC search input)

    tr_all<<<2048 + 128, 256, 0, stream>>>(in_search, in_kernel, strA, ktr);
    prep_all<<<5121, 256, 0, stream>>>(wk, wsw, wh1, wh2,
                                       gk, bk, mk, vk, gs, bs, ms, vs,
                                       gh, bh, mh, vh, bh2,
                                       Wk2, Ws2, Wh1, Wh2,
                                       sk, tk, ss, ts, sh, th, s5, t5);

    // stage 1: kernel tower  -> kfeat NHWC [128*25, 256]
    conv_gemm<9, true, u16, true><<<dim3(2, 25), 256, 0, stream>>>(
        ktr, Wk2, sk, tk, kfeat, 7, 7, 5, 5);
    // stage 2: search tower  -> sfeat NHWC [128*841, 256]  (round-3 kernel)
    conv_gemm8<9><<<dim3(421), 512, 0, stream>>>(
        strA, Ws2, ss, ts, sfeat, 31, 31, 29, 29, 128 * 841);
    // stage 3: depthwise xcorr -> feat NHWC [128*625, 256]
    xcorr_kernel<<<128 * 5, 256, 0, stream>>>(sfeat, kfeat, feat);
    // stage 4+5 fused: head 1x1+BN+ReLU then 1x1+bias -> out NCHW fp32
    head_fused<<<625, 512, 0, stream>>>(feat, Wh1, Wh2, sh, th, t5, out);

    (void)in_sizes; (void)n_in; (void)out_size; (void)ws_size;
}